// Round 1
// baseline (3375.209 us; speedup 1.0000x reference)
//
#include <hip/hip_runtime.h>
#include <hip/hip_bf16.h>

#define NEG_SLOPE 0.2f

// ---------- helpers ----------

__device__ __forceinline__ unsigned fkey(float f) {
    unsigned u = __float_as_uint(f);
    return (u & 0x80000000u) ? ~u : (u | 0x80000000u);
}
__device__ __forceinline__ float funkey(unsigned u) {
    return (u & 0x80000000u) ? __uint_as_float(u ^ 0x80000000u)
                             : __uint_as_float(~u);
}
__device__ __forceinline__ void edge_sd(int e, const int* __restrict__ srcs,
                                        const int* __restrict__ dsts, int E,
                                        int& s, int& d) {
    if (e < E) { s = srcs[e]; d = dsts[e]; }
    else       { s = e - E;   d = s;       }
}

// ---------- GEMM layer 0: [N,256] @ [256,64] ----------

__global__ __launch_bounds__(256) void gemm0_k(const float* __restrict__ x,
                                               const float* __restrict__ W,
                                               float* __restrict__ h, int N) {
    __shared__ float xs[16][65];
    __shared__ float Ws[64][64];
    int n0  = blockIdx.x * 16;
    int tid = threadIdx.x;
    int tn  = tid >> 4;          // 0..15 node
    int tc  = (tid & 15) * 4;    // 0..60 channel base
    float acc0 = 0.f, acc1 = 0.f, acc2 = 0.f, acc3 = 0.f;
    for (int kt = 0; kt < 256; kt += 64) {
        for (int i = tid; i < 16 * 64; i += 256) {
            int n = i >> 6, k = i & 63;
            int gn = n0 + n;
            xs[n][k] = (gn < N) ? x[(size_t)gn * 256 + kt + k] : 0.f;
        }
        for (int i = tid; i < 64 * 64; i += 256) {
            int k = i >> 6, c = i & 63;
            Ws[k][c] = W[(size_t)(kt + k) * 64 + c];
        }
        __syncthreads();
        #pragma unroll
        for (int kk = 0; kk < 64; ++kk) {
            float xv = xs[tn][kk];
            acc0 += xv * Ws[kk][tc + 0];
            acc1 += xv * Ws[kk][tc + 1];
            acc2 += xv * Ws[kk][tc + 2];
            acc3 += xv * Ws[kk][tc + 3];
        }
        __syncthreads();
    }
    int gn = n0 + tn;
    if (gn < N) {
        float4 v = make_float4(acc0, acc1, acc2, acc3);
        *(float4*)&h[(size_t)gn * 64 + tc] = v;
    }
}

// ---------- GEMM layers 1/2: [N,64] @ [64,COUT] ----------

template <int COUT>
__global__ __launch_bounds__(256) void gemm64_k(const float* __restrict__ x,
                                                const float* __restrict__ W,
                                                float* __restrict__ h, int N) {
    __shared__ float xs[64][65];
    __shared__ float Ws[64][COUT];
    int n0  = blockIdx.x * 64;
    int tid = threadIdx.x;
    for (int i = tid; i < 64 * 64; i += 256) {
        int n = i >> 6, k = i & 63;
        int gn = n0 + n;
        xs[n][k] = (gn < N) ? x[(size_t)gn * 64 + k] : 0.f;
    }
    for (int i = tid; i < 64 * COUT; i += 256) {
        int k = i / COUT, c = i % COUT;
        Ws[k][c] = W[(size_t)k * COUT + c];
    }
    __syncthreads();
    for (int i = tid; i < 64 * COUT; i += 256) {
        int n = i / COUT, c = i % COUT;
        float acc = 0.f;
        #pragma unroll
        for (int k = 0; k < 64; ++k) acc += xs[n][k] * Ws[k][c];
        int gn = n0 + n;
        if (gn < N) h[(size_t)gn * COUT + c] = acc;
    }
}

// ---------- per-node attention logits ----------

template <int HH, int CC>
__global__ void att_k(const float* __restrict__ h,
                      const float* __restrict__ a_src,
                      const float* __restrict__ a_dst,
                      float* __restrict__ as_, float* __restrict__ ad_, int N) {
    int idx = blockIdx.x * blockDim.x + threadIdx.x;
    if (idx >= N * HH) return;
    int n = idx / HH, hd = idx % HH;
    const float* hp = h + ((size_t)n * HH + hd) * CC;
    float s = 0.f, d = 0.f;
    #pragma unroll
    for (int j = 0; j < CC; ++j) {
        float v = hp[j];
        s += v * a_src[hd * CC + j];
        d += v * a_dst[hd * CC + j];
    }
    as_[idx] = s;
    ad_[idx] = d;
}

// ---------- edge pass 1: segment max ----------

template <int HH>
__global__ void edge_max_k(const float* __restrict__ as_,
                           const float* __restrict__ ad_,
                           const int* __restrict__ srcs,
                           const int* __restrict__ dsts,
                           unsigned* __restrict__ m_u, int E, int Etot) {
    int idx = blockIdx.x * blockDim.x + threadIdx.x;
    if (idx >= Etot * HH) return;
    int e = idx / HH, hd = idx % HH;
    int s, d;
    edge_sd(e, srcs, dsts, E, s, d);
    float v = as_[s * HH + hd] + ad_[d * HH + hd];
    v = v > 0.f ? v : NEG_SLOPE * v;
    atomicMax(&m_u[d * HH + hd], fkey(v));
}

// ---------- edge pass 2: segment sum of exp ----------

template <int HH>
__global__ void edge_sum_k(const float* __restrict__ as_,
                           const float* __restrict__ ad_,
                           const int* __restrict__ srcs,
                           const int* __restrict__ dsts,
                           const unsigned* __restrict__ m_u,
                           float* __restrict__ s_sum, int E, int Etot) {
    int idx = blockIdx.x * blockDim.x + threadIdx.x;
    if (idx >= Etot * HH) return;
    int e = idx / HH, hd = idx % HH;
    int s, d;
    edge_sd(e, srcs, dsts, E, s, d);
    float v = as_[s * HH + hd] + ad_[d * HH + hd];
    v = v > 0.f ? v : NEG_SLOPE * v;
    float mm = funkey(m_u[d * HH + hd]);
    atomicAdd(&s_sum[d * HH + hd], expf(v - mm));
}

// ---------- edge pass 3: weighted aggregation (H=8, C=8, width 64) ----------

__global__ __launch_bounds__(256) void edge_aggr64_k(
    const float* __restrict__ h, const float* __restrict__ as_,
    const float* __restrict__ ad_, const int* __restrict__ srcs,
    const int* __restrict__ dsts, const unsigned* __restrict__ m_u,
    const float* __restrict__ s_sum, float* __restrict__ out, int E, int Etot) {
    int slot = blockIdx.x * 4 + (threadIdx.x >> 6);
    if (slot >= Etot) return;
    int c = threadIdx.x & 63;
    int s, d;
    edge_sd(slot, srcs, dsts, E, s, d);
    int hd = c >> 3;
    float v = as_[s * 8 + hd] + ad_[d * 8 + hd];
    v = v > 0.f ? v : NEG_SLOPE * v;
    float mm = funkey(m_u[d * 8 + hd]);
    float alpha = expf(v - mm) / (s_sum[d * 8 + hd] + 1e-16f);
    atomicAdd(&out[(size_t)d * 64 + c], h[(size_t)s * 64 + c] * alpha);
}

// ---------- edge pass 3 for layer 2 (H=1, C=40) ----------

__global__ void edge_aggr40_k(const float* __restrict__ h,
                              const float* __restrict__ as_,
                              const float* __restrict__ ad_,
                              const int* __restrict__ srcs,
                              const int* __restrict__ dsts,
                              const unsigned* __restrict__ m_u,
                              const float* __restrict__ s_sum,
                              float* __restrict__ out, int E, int Etot) {
    int idx = blockIdx.x * blockDim.x + threadIdx.x;
    int tot = Etot * 40;
    if (idx >= tot) return;
    int e = idx / 40, c = idx % 40;
    int s, d;
    edge_sd(e, srcs, dsts, E, s, d);
    float v = as_[s] + ad_[d];
    v = v > 0.f ? v : NEG_SLOPE * v;
    float mm = funkey(m_u[d]);
    float alpha = expf(v - mm) / (s_sum[d] + 1e-16f);
    atomicAdd(&out[(size_t)d * 40 + c], h[(size_t)s * 40 + c] * alpha);
}

// ---------- bias add (C=64) ----------

__global__ void bias_add64_k(float* __restrict__ out,
                             const float* __restrict__ b, int total) {
    int idx = blockIdx.x * blockDim.x + threadIdx.x;
    if (idx < total) out[idx] += b[idx & 63];
}

// ---------- final: +bias, log_softmax over 40 classes ----------

__global__ void final_k(const float* __restrict__ agg,
                        const float* __restrict__ b, float* __restrict__ out,
                        int N) {
    int n = blockIdx.x * blockDim.x + threadIdx.x;
    if (n >= N) return;
    float v[40];
    float mx = -1e30f;
    #pragma unroll
    for (int j = 0; j < 40; ++j) {
        v[j] = agg[(size_t)n * 40 + j] + b[j];
        mx = fmaxf(mx, v[j]);
    }
    float ssum = 0.f;
    #pragma unroll
    for (int j = 0; j < 40; ++j) ssum += expf(v[j] - mx);
    float lg = logf(ssum);
    #pragma unroll
    for (int j = 0; j < 40; ++j) out[(size_t)n * 40 + j] = v[j] - mx - lg;
}

// ---------- launch ----------

extern "C" void kernel_launch(void* const* d_in, const int* in_sizes, int n_in,
                              void* d_out, int out_size, void* d_ws,
                              size_t ws_size, hipStream_t stream) {
    const float* features = (const float*)d_in[0];
    const int* edge_index = (const int*)d_in[1];
    const float* W0 = (const float*)d_in[2];
    const float* as0 = (const float*)d_in[3];
    const float* ad0 = (const float*)d_in[4];
    const float* b0 = (const float*)d_in[5];
    const float* W1 = (const float*)d_in[6];
    const float* as1 = (const float*)d_in[7];
    const float* ad1 = (const float*)d_in[8];
    const float* b1 = (const float*)d_in[9];
    const float* W2 = (const float*)d_in[10];
    const float* as2 = (const float*)d_in[11];
    const float* ad2 = (const float*)d_in[12];
    const float* b2 = (const float*)d_in[13];

    int N = in_sizes[0] / 256;
    int E = in_sizes[1] / 2;
    int Etot = E + N;
    const int* srcs = edge_index;
    const int* dsts = edge_index + E;

    float* ws = (float*)d_ws;
    float* Hbuf = ws;                          // N*64
    float* Abuf = Hbuf + (size_t)N * 64;       // N*64
    float* Bbuf = Abuf + (size_t)N * 64;       // N*64
    float* asb = Bbuf + (size_t)N * 64;        // N*8
    float* adb = asb + (size_t)N * 8;          // N*8
    float* mbf = adb + (size_t)N * 8;          // N*8 (uint storage)
    float* sb = mbf + (size_t)N * 8;           // N*8
    unsigned* mb = (unsigned*)mbf;

    const int B = 256;
    int gE8 = (Etot * 8 + B - 1) / B;
    int gE1 = (Etot + B - 1) / B;
    int gAg = (Etot + 3) / 4;
    int gAg40 = (Etot * 40 + B - 1) / B;
    int gN8 = (N * 8 + B - 1) / B;
    int gN1 = (N + B - 1) / B;
    int gN64 = (N * 64 + B - 1) / B;

    // ---------------- layer 0 ----------------
    gemm0_k<<<(N + 15) / 16, B, 0, stream>>>(features, W0, Hbuf, N);
    att_k<8, 8><<<gN8, B, 0, stream>>>(Hbuf, as0, ad0, asb, adb, N);
    hipMemsetAsync(mb, 0, (size_t)N * 8 * 4, stream);
    hipMemsetAsync(sb, 0, (size_t)N * 8 * 4, stream);
    hipMemsetAsync(Abuf, 0, (size_t)N * 64 * 4, stream);
    edge_max_k<8><<<gE8, B, 0, stream>>>(asb, adb, srcs, dsts, mb, E, Etot);
    edge_sum_k<8><<<gE8, B, 0, stream>>>(asb, adb, srcs, dsts, mb, sb, E, Etot);
    edge_aggr64_k<<<gAg, B, 0, stream>>>(Hbuf, asb, adb, srcs, dsts, mb, sb,
                                         Abuf, E, Etot);
    bias_add64_k<<<gN64, B, 0, stream>>>(Abuf, b0, N * 64);

    // ---------------- layer 1 ----------------
    gemm64_k<64><<<(N + 63) / 64, B, 0, stream>>>(Abuf, W1, Hbuf, N);
    att_k<8, 8><<<gN8, B, 0, stream>>>(Hbuf, as1, ad1, asb, adb, N);
    hipMemsetAsync(mb, 0, (size_t)N * 8 * 4, stream);
    hipMemsetAsync(sb, 0, (size_t)N * 8 * 4, stream);
    hipMemsetAsync(Bbuf, 0, (size_t)N * 64 * 4, stream);
    edge_max_k<8><<<gE8, B, 0, stream>>>(asb, adb, srcs, dsts, mb, E, Etot);
    edge_sum_k<8><<<gE8, B, 0, stream>>>(asb, adb, srcs, dsts, mb, sb, E, Etot);
    edge_aggr64_k<<<gAg, B, 0, stream>>>(Hbuf, asb, adb, srcs, dsts, mb, sb,
                                         Bbuf, E, Etot);
    bias_add64_k<<<gN64, B, 0, stream>>>(Bbuf, b1, N * 64);

    // ---------------- layer 2 ----------------
    gemm64_k<40><<<(N + 63) / 64, B, 0, stream>>>(Bbuf, W2, Hbuf, N);
    att_k<1, 40><<<gN1, B, 0, stream>>>(Hbuf, as2, ad2, asb, adb, N);
    hipMemsetAsync(mb, 0, (size_t)N * 4, stream);
    hipMemsetAsync(sb, 0, (size_t)N * 4, stream);
    hipMemsetAsync(Abuf, 0, (size_t)N * 40 * 4, stream);
    edge_max_k<1><<<gE1, B, 0, stream>>>(asb, adb, srcs, dsts, mb, E, Etot);
    edge_sum_k<1><<<gE1, B, 0, stream>>>(asb, adb, srcs, dsts, mb, sb, E, Etot);
    edge_aggr40_k<<<gAg40, B, 0, stream>>>(Hbuf, asb, adb, srcs, dsts, mb, sb,
                                           Abuf, E, Etot);
    final_k<<<gN1, B, 0, stream>>>(Abuf, b2, d_out ? (float*)d_out : Abuf, N);
}

// Round 2
// 1440.023 us; speedup vs baseline: 2.3439x; 2.3439x over previous
//
#include <hip/hip_runtime.h>
#include <hip/hip_bf16.h>

#define NEG_SLOPE 0.2f

// =================== CSR build ===================

__global__ void hist_k(const int* __restrict__ srcs,
                       const int* __restrict__ dsts, int* __restrict__ deg,
                       int E, int Etot) {
    int e = blockIdx.x * blockDim.x + threadIdx.x;
    if (e >= Etot) return;
    int d = (e < E) ? dsts[e] : (e - E);
    atomicAdd(&deg[d], 1);
}

// phase A: per-block inclusive scan; partials go to row_ptr+1, block sums out
__global__ __launch_bounds__(256) void scanA_k(const int* __restrict__ deg,
                                               int* __restrict__ row_ptr1,
                                               int* __restrict__ bsum, int n) {
    __shared__ int tmp[256];
    int i = blockIdx.x * 256 + threadIdx.x;
    int v = (i < n) ? deg[i] : 0;
    tmp[threadIdx.x] = v;
    __syncthreads();
    for (int off = 1; off < 256; off <<= 1) {
        int t = (threadIdx.x >= off) ? tmp[threadIdx.x - off] : 0;
        __syncthreads();
        tmp[threadIdx.x] += t;
        __syncthreads();
    }
    if (i < n) row_ptr1[i] = tmp[threadIdx.x];
    if (threadIdx.x == 255) bsum[blockIdx.x] = tmp[255];
}

__global__ __launch_bounds__(1024) void scanB_k(int* __restrict__ bsum,
                                                int nb) {
    __shared__ int tmp[1024];
    int v = (threadIdx.x < nb) ? bsum[threadIdx.x] : 0;
    tmp[threadIdx.x] = v;
    __syncthreads();
    for (int off = 1; off < 1024; off <<= 1) {
        int t = (threadIdx.x >= off) ? tmp[threadIdx.x - off] : 0;
        __syncthreads();
        tmp[threadIdx.x] += t;
        __syncthreads();
    }
    if (threadIdx.x < nb) bsum[threadIdx.x] = tmp[threadIdx.x];
}

// phase C: finalize row_ptr (exclusive; row_ptr[0]=0) and copy to cursor
__global__ __launch_bounds__(256) void scanC_k(int* __restrict__ row_ptr,
                                               const int* __restrict__ bsum,
                                               int* __restrict__ cursor,
                                               int n) {
    int i = blockIdx.x * 256 + threadIdx.x;
    if (i < n) {
        int v = row_ptr[i + 1] + (blockIdx.x ? bsum[blockIdx.x - 1] : 0);
        row_ptr[i + 1] = v;
        cursor[i + 1] = v;
    }
    if (i == 0) { row_ptr[0] = 0; cursor[0] = 0; }
}

__global__ void scatter_k(const int* __restrict__ srcs,
                          const int* __restrict__ dsts,
                          int* __restrict__ cursor, int* __restrict__ csr_src,
                          int E, int Etot) {
    int e = blockIdx.x * blockDim.x + threadIdx.x;
    if (e >= Etot) return;
    int s, d;
    if (e < E) { s = srcs[e]; d = dsts[e]; }
    else       { s = e - E;   d = s; }
    int pos = atomicAdd(&cursor[d], 1);
    csr_src[pos] = s;
}

// =================== GEMM layer 0: [N,256] @ [256,64] ===================

__global__ __launch_bounds__(256) void gemm0_k(const float* __restrict__ x,
                                               const float* __restrict__ W,
                                               float* __restrict__ h, int N) {
    __shared__ float xs[16][65];
    __shared__ float Ws[64][64];
    int n0  = blockIdx.x * 16;
    int tid = threadIdx.x;
    int tn  = tid >> 4;
    int tc  = (tid & 15) * 4;
    float acc0 = 0.f, acc1 = 0.f, acc2 = 0.f, acc3 = 0.f;
    for (int kt = 0; kt < 256; kt += 64) {
        for (int i = tid; i < 16 * 64; i += 256) {
            int n = i >> 6, k = i & 63;
            int gn = n0 + n;
            xs[n][k] = (gn < N) ? x[(size_t)gn * 256 + kt + k] : 0.f;
        }
        for (int i = tid; i < 64 * 64; i += 256) {
            int k = i >> 6, c = i & 63;
            Ws[k][c] = W[(size_t)(kt + k) * 64 + c];
        }
        __syncthreads();
        #pragma unroll
        for (int kk = 0; kk < 64; ++kk) {
            float xv = xs[tn][kk];
            acc0 += xv * Ws[kk][tc + 0];
            acc1 += xv * Ws[kk][tc + 1];
            acc2 += xv * Ws[kk][tc + 2];
            acc3 += xv * Ws[kk][tc + 3];
        }
        __syncthreads();
    }
    int gn = n0 + tn;
    if (gn < N) {
        float4 v = make_float4(acc0, acc1, acc2, acc3);
        *(float4*)&h[(size_t)gn * 64 + tc] = v;
    }
}

// =================== GEMM layers 1/2: [N,64] @ [64,COUT] ===================

template <int COUT>
__global__ __launch_bounds__(256) void gemm64_k(const float* __restrict__ x,
                                                const float* __restrict__ W,
                                                float* __restrict__ h, int N) {
    __shared__ float xs[64][65];
    __shared__ float Ws[64][COUT];
    int n0  = blockIdx.x * 64;
    int tid = threadIdx.x;
    for (int i = tid; i < 64 * 64; i += 256) {
        int n = i >> 6, k = i & 63;
        int gn = n0 + n;
        xs[n][k] = (gn < N) ? x[(size_t)gn * 64 + k] : 0.f;
    }
    for (int i = tid; i < 64 * COUT; i += 256) {
        int k = i / COUT, c = i % COUT;
        Ws[k][c] = W[(size_t)k * COUT + c];
    }
    __syncthreads();
    for (int i = tid; i < 64 * COUT; i += 256) {
        int n = i / COUT, c = i % COUT;
        float acc = 0.f;
        #pragma unroll
        for (int k = 0; k < 64; ++k) acc += xs[n][k] * Ws[k][c];
        int gn = n0 + n;
        if (gn < N) h[(size_t)gn * COUT + c] = acc;
    }
}

// =================== per-node attention logits ===================

template <int HH, int CC>
__global__ void att_k(const float* __restrict__ h,
                      const float* __restrict__ a_src,
                      const float* __restrict__ a_dst,
                      float* __restrict__ as_, float* __restrict__ ad_, int N) {
    int idx = blockIdx.x * blockDim.x + threadIdx.x;
    if (idx >= N * HH) return;
    int n = idx / HH, hd = idx % HH;
    const float* hp = h + ((size_t)n * HH + hd) * CC;
    float s = 0.f, d = 0.f;
    #pragma unroll
    for (int j = 0; j < CC; ++j) {
        float v = hp[j];
        s += v * a_src[hd * CC + j];
        d += v * a_dst[hd * CC + j];
    }
    as_[idx] = s;
    ad_[idx] = d;
}

// =================== fused softmax+aggregate, width 64 (H=8,C=8) =========
// one wave per dst node; lane = channel; online softmax over incoming edges

__global__ __launch_bounds__(256) void aggr_csr64_k(
    const float* __restrict__ h, const float* __restrict__ asb,
    const float* __restrict__ adb, const int* __restrict__ row_ptr,
    const int* __restrict__ csr_src, const float* __restrict__ bias,
    float* __restrict__ out, int N) {
    int node = blockIdx.x * 4 + (threadIdx.x >> 6);
    if (node >= N) return;
    int lane = threadIdx.x & 63;
    int hd = lane >> 3;
    int beg = row_ptr[node], end = row_ptr[node + 1];
    float ad = adb[node * 8 + hd];
    float m = -1e30f, l = 0.f, acc = 0.f;
    int s = csr_src[beg];
    for (int i = beg; i < end; ++i) {
        int s_next = (i + 1 < end) ? csr_src[i + 1] : s;
        float as = asb[s * 8 + hd];
        float hv = h[(size_t)s * 64 + lane];
        float v = as + ad;
        v = v > 0.f ? v : NEG_SLOPE * v;
        if (v > m) {
            float r = __expf(m - v);
            l *= r;
            acc *= r;
            m = v;
        }
        float w = __expf(v - m);
        l += w;
        acc += w * hv;
        s = s_next;
    }
    out[(size_t)node * 64 + lane] = acc / (l + 1e-16f) + bias[lane];
}

// =================== fused softmax+aggregate, width 40 (H=1,C=40) ========

__global__ __launch_bounds__(256) void aggr_csr40_k(
    const float* __restrict__ h, const float* __restrict__ asb,
    const float* __restrict__ adb, const int* __restrict__ row_ptr,
    const int* __restrict__ csr_src, float* __restrict__ out, int N) {
    int node = blockIdx.x * 4 + (threadIdx.x >> 6);
    if (node >= N) return;
    int lane = threadIdx.x & 63;
    int beg = row_ptr[node], end = row_ptr[node + 1];
    float ad = adb[node];
    float m = -1e30f, l = 0.f, acc = 0.f;
    int s = csr_src[beg];
    for (int i = beg; i < end; ++i) {
        int s_next = (i + 1 < end) ? csr_src[i + 1] : s;
        float as = asb[s];
        float hv = (lane < 40) ? h[(size_t)s * 40 + lane] : 0.f;
        float v = as + ad;
        v = v > 0.f ? v : NEG_SLOPE * v;
        if (v > m) {
            float r = __expf(m - v);
            l *= r;
            acc *= r;
            m = v;
        }
        float w = __expf(v - m);
        l += w;
        acc += w * hv;
        s = s_next;
    }
    if (lane < 40) out[(size_t)node * 40 + lane] = acc / (l + 1e-16f);
}

// =================== final: +bias, log_softmax over 40 classes ===========

__global__ void final_k(const float* __restrict__ agg,
                        const float* __restrict__ b, float* __restrict__ out,
                        int N) {
    int n = blockIdx.x * blockDim.x + threadIdx.x;
    if (n >= N) return;
    float v[40];
    float mx = -1e30f;
    #pragma unroll
    for (int j = 0; j < 40; ++j) {
        v[j] = agg[(size_t)n * 40 + j] + b[j];
        mx = fmaxf(mx, v[j]);
    }
    float ssum = 0.f;
    #pragma unroll
    for (int j = 0; j < 40; ++j) ssum += __expf(v[j] - mx);
    float lg = __logf(ssum);
    #pragma unroll
    for (int j = 0; j < 40; ++j) out[(size_t)n * 40 + j] = v[j] - mx - lg;
}

// =================== launch ===================

extern "C" void kernel_launch(void* const* d_in, const int* in_sizes, int n_in,
                              void* d_out, int out_size, void* d_ws,
                              size_t ws_size, hipStream_t stream) {
    const float* features = (const float*)d_in[0];
    const int* edge_index = (const int*)d_in[1];
    const float* W0 = (const float*)d_in[2];
    const float* as0 = (const float*)d_in[3];
    const float* ad0 = (const float*)d_in[4];
    const float* b0 = (const float*)d_in[5];
    const float* W1 = (const float*)d_in[6];
    const float* as1 = (const float*)d_in[7];
    const float* ad1 = (const float*)d_in[8];
    const float* b1 = (const float*)d_in[9];
    const float* W2 = (const float*)d_in[10];
    const float* as2 = (const float*)d_in[11];
    const float* ad2 = (const float*)d_in[12];
    const float* b2 = (const float*)d_in[13];

    int N = in_sizes[0] / 256;
    int E = in_sizes[1] / 2;
    int Etot = E + N;
    const int* srcs = edge_index;
    const int* dsts = edge_index + E;

    // workspace layout (floats)
    float* ws = (float*)d_ws;
    float* Hbuf = ws;                              // N*64 (also holds N*40 h2)
    float* Abuf = Hbuf + (size_t)N * 64;           // N*64 (x1 / x2 / agg2)
    float* asb  = Abuf + (size_t)N * 64;           // N*8
    float* adb  = asb + (size_t)N * 8;             // N*8
    int* row_ptr = (int*)(adb + (size_t)N * 8);    // N+1
    int* cursor  = row_ptr + (N + 1);              // N+1 (also deg)
    int* bsum    = cursor + (N + 1);               // 1024
    int* csr_src = bsum + 1024;                    // Etot

    const int B = 256;
    int gE  = (Etot + B - 1) / B;
    int gN8 = (N * 8 + B - 1) / B;
    int gN1 = (N + B - 1) / B;
    int gAg = (N + 3) / 4;
    int nb  = (N + 255) / 256;

    // ---------- CSR build (deg lives in cursor buffer) ----------
    hipMemsetAsync(cursor, 0, (size_t)(N + 1) * 4, stream);
    hist_k<<<gE, B, 0, stream>>>(srcs, dsts, cursor, E, Etot);
    scanA_k<<<nb, 256, 0, stream>>>(cursor, row_ptr + 1, bsum, N);
    scanB_k<<<1, 1024, 0, stream>>>(bsum, nb);
    scanC_k<<<nb, 256, 0, stream>>>(row_ptr, bsum, cursor, N);
    scatter_k<<<gE, B, 0, stream>>>(srcs, dsts, cursor, csr_src, E, Etot);

    // ---------------- layer 0 ----------------
    gemm0_k<<<(N + 15) / 16, B, 0, stream>>>(features, W0, Hbuf, N);
    att_k<8, 8><<<gN8, B, 0, stream>>>(Hbuf, as0, ad0, asb, adb, N);
    aggr_csr64_k<<<gAg, B, 0, stream>>>(Hbuf, asb, adb, row_ptr, csr_src, b0,
                                        Abuf, N);

    // ---------------- layer 1 ----------------
    gemm64_k<64><<<(N + 63) / 64, B, 0, stream>>>(Abuf, W1, Hbuf, N);
    att_k<8, 8><<<gN8, B, 0, stream>>>(Hbuf, as1, ad1, asb, adb, N);
    aggr_csr64_k<<<gAg, B, 0, stream>>>(Hbuf, asb, adb, row_ptr, csr_src, b1,
                                        Abuf, N);

    // ---------------- layer 2 ----------------
    gemm64_k<40><<<(N + 63) / 64, B, 0, stream>>>(Abuf, W2, Hbuf, N);
    att_k<1, 40><<<gN1, B, 0, stream>>>(Hbuf, as2, ad2, asb, adb, N);
    aggr_csr40_k<<<gAg, B, 0, stream>>>(Hbuf, asb, adb, row_ptr, csr_src,
                                        Abuf, N);
    final_k<<<gN1, B, 0, stream>>>(Abuf, b2, (float*)d_out, N);
}

// Round 3
// 1187.228 us; speedup vs baseline: 2.8429x; 1.2129x over previous
//
#include <hip/hip_runtime.h>
#include <hip/hip_bf16.h>

#define NEG_SLOPE 0.2f
#define EPB 4096  // edges per block in bucket phases

// =================== CSR build: two-level counting sort ===================
// bucket = dst >> 8 (256 nodes per bucket)

__global__ __launch_bounds__(256) void bucket_hist_k(
    const int* __restrict__ dsts, int* __restrict__ bcnt, int E, int Etot,
    int nbuck) {
    __shared__ int lh[512];
    for (int i = threadIdx.x; i < nbuck; i += 256) lh[i] = 0;
    __syncthreads();
    int base = blockIdx.x * EPB;
    int cnt = Etot - base;
    if (cnt > EPB) cnt = EPB;
    for (int i = threadIdx.x; i < cnt; i += 256) {
        int e = base + i;
        int d = (e < E) ? dsts[e] : (e - E);
        atomicAdd(&lh[d >> 8], 1);
    }
    __syncthreads();
    for (int i = threadIdx.x; i < nbuck; i += 256) {
        int c = lh[i];
        if (c) atomicAdd(&bcnt[i], c);
    }
}

__global__ __launch_bounds__(512) void bucket_scan_k(
    const int* __restrict__ bcnt, int* __restrict__ bptr,
    int* __restrict__ bcur, int nbuck, int Etot) {
    __shared__ int tmp[512];
    int t = threadIdx.x;
    int v = (t < nbuck) ? bcnt[t] : 0;
    tmp[t] = v;
    __syncthreads();
    for (int off = 1; off < 512; off <<= 1) {
        int x = (t >= off) ? tmp[t - off] : 0;
        __syncthreads();
        tmp[t] += x;
        __syncthreads();
    }
    int excl = tmp[t] - v;
    if (t < nbuck) { bptr[t] = excl; bcur[t] = excl; }
    if (t == 0) bptr[nbuck] = Etot;
}

__global__ __launch_bounds__(256) void bucket_scatter_k(
    const int* __restrict__ srcs, const int* __restrict__ dsts,
    int* __restrict__ bcur, int2* __restrict__ pairs, int E, int Etot,
    int nbuck) {
    __shared__ int lh[512];
    __shared__ int lbase[512];
    for (int i = threadIdx.x; i < nbuck; i += 256) lh[i] = 0;
    __syncthreads();
    int base = blockIdx.x * EPB;
    int cnt = Etot - base;
    if (cnt > EPB) cnt = EPB;
    for (int i = threadIdx.x; i < cnt; i += 256) {
        int e = base + i;
        int d = (e < E) ? dsts[e] : (e - E);
        atomicAdd(&lh[d >> 8], 1);
    }
    __syncthreads();
    for (int i = threadIdx.x; i < nbuck; i += 256) {
        int c = lh[i];
        lbase[i] = c ? atomicAdd(&bcur[i], c) : 0;
    }
    __syncthreads();
    for (int i = threadIdx.x; i < nbuck; i += 256) lh[i] = 0;
    __syncthreads();
    for (int i = threadIdx.x; i < cnt; i += 256) {
        int e = base + i;
        int s, d;
        if (e < E) { s = srcs[e]; d = dsts[e]; }
        else       { s = e - E;   d = s; }
        int b = d >> 8;
        int off = atomicAdd(&lh[b], 1);
        pairs[lbase[b] + off] = make_int2(s, d);
    }
}

__global__ __launch_bounds__(256) void bucket_sort_k(
    const int2* __restrict__ pairs, const int* __restrict__ bptr,
    int* __restrict__ row_ptr, int* __restrict__ csr_src, int N, int Etot,
    int nbuck) {
    __shared__ int lh[256];
    __shared__ int lscan[256];
    int b = blockIdx.x;
    int n0 = b << 8;
    int e0 = bptr[b], e1 = bptr[b + 1];
    int t = threadIdx.x;
    lh[t] = 0;
    __syncthreads();
    for (int e = e0 + t; e < e1; e += 256)
        atomicAdd(&lh[pairs[e].y - n0], 1);
    __syncthreads();
    int v = lh[t];
    lscan[t] = v;
    __syncthreads();
    for (int off = 1; off < 256; off <<= 1) {
        int x = (t >= off) ? lscan[t - off] : 0;
        __syncthreads();
        lscan[t] += x;
        __syncthreads();
    }
    int start = e0 + lscan[t] - v;
    int n = n0 + t;
    if (n < N) row_ptr[n] = start;
    lh[t] = start;  // reuse as cursor
    __syncthreads();
    for (int e = e0 + t; e < e1; e += 256) {
        int2 p = pairs[e];
        int pos = atomicAdd(&lh[p.y - n0], 1);
        csr_src[pos] = p.x;
    }
    if (b == nbuck - 1 && t == 0) row_ptr[N] = Etot;
}

// =================== GEMM layer 0: [N,256] @ [256,64] ===================

__global__ __launch_bounds__(256) void gemm0_k(const float* __restrict__ x,
                                               const float* __restrict__ W,
                                               float* __restrict__ h, int N) {
    __shared__ float xs[16][65];
    __shared__ float Ws[64][64];
    int n0  = blockIdx.x * 16;
    int tid = threadIdx.x;
    int tn  = tid >> 4;
    int tc  = (tid & 15) * 4;
    float acc0 = 0.f, acc1 = 0.f, acc2 = 0.f, acc3 = 0.f;
    for (int kt = 0; kt < 256; kt += 64) {
        for (int i = tid; i < 16 * 64; i += 256) {
            int n = i >> 6, k = i & 63;
            int gn = n0 + n;
            xs[n][k] = (gn < N) ? x[(size_t)gn * 256 + kt + k] : 0.f;
        }
        for (int i = tid; i < 64 * 64; i += 256) {
            int k = i >> 6, c = i & 63;
            Ws[k][c] = W[(size_t)(kt + k) * 64 + c];
        }
        __syncthreads();
        #pragma unroll
        for (int kk = 0; kk < 64; ++kk) {
            float xv = xs[tn][kk];
            acc0 += xv * Ws[kk][tc + 0];
            acc1 += xv * Ws[kk][tc + 1];
            acc2 += xv * Ws[kk][tc + 2];
            acc3 += xv * Ws[kk][tc + 3];
        }
        __syncthreads();
    }
    int gn = n0 + tn;
    if (gn < N) {
        float4 v = make_float4(acc0, acc1, acc2, acc3);
        *(float4*)&h[(size_t)gn * 64 + tc] = v;
    }
}

// =================== GEMM layers 1/2: [N,64] @ [64,COUT] ===================

template <int COUT>
__global__ __launch_bounds__(256) void gemm64_k(const float* __restrict__ x,
                                                const float* __restrict__ W,
                                                float* __restrict__ h, int N) {
    __shared__ float xs[64][65];
    __shared__ float Ws[64][COUT];
    int n0  = blockIdx.x * 64;
    int tid = threadIdx.x;
    for (int i = tid; i < 64 * 64; i += 256) {
        int n = i >> 6, k = i & 63;
        int gn = n0 + n;
        xs[n][k] = (gn < N) ? x[(size_t)gn * 64 + k] : 0.f;
    }
    for (int i = tid; i < 64 * COUT; i += 256) {
        int k = i / COUT, c = i % COUT;
        Ws[k][c] = W[(size_t)k * COUT + c];
    }
    __syncthreads();
    for (int i = tid; i < 64 * COUT; i += 256) {
        int n = i / COUT, c = i % COUT;
        float acc = 0.f;
        #pragma unroll
        for (int k = 0; k < 64; ++k) acc += xs[n][k] * Ws[k][c];
        int gn = n0 + n;
        if (gn < N) h[(size_t)gn * COUT + c] = acc;
    }
}

// =================== per-node attention logits ===================

template <int HH, int CC>
__global__ void att_k(const float* __restrict__ h,
                      const float* __restrict__ a_src,
                      const float* __restrict__ a_dst,
                      float* __restrict__ as_, float* __restrict__ ad_, int N) {
    int idx = blockIdx.x * blockDim.x + threadIdx.x;
    if (idx >= N * HH) return;
    int n = idx / HH, hd = idx % HH;
    const float* hp = h + ((size_t)n * HH + hd) * CC;
    float s = 0.f, d = 0.f;
    #pragma unroll
    for (int j = 0; j < CC; ++j) {
        float v = hp[j];
        s += v * a_src[hd * CC + j];
        d += v * a_dst[hd * CC + j];
    }
    as_[idx] = s;
    ad_[idx] = d;
}

// =================== fused softmax+aggregate, width 64 (H=8,C=8) =========

__global__ __launch_bounds__(256) void aggr_csr64_k(
    const float* __restrict__ h, const float* __restrict__ asb,
    const float* __restrict__ adb, const int* __restrict__ row_ptr,
    const int* __restrict__ csr_src, const float* __restrict__ bias,
    float* __restrict__ out, int N) {
    int node = blockIdx.x * 4 + (threadIdx.x >> 6);
    if (node >= N) return;
    int lane = threadIdx.x & 63;
    int hd = lane >> 3;
    int beg = row_ptr[node], end = row_ptr[node + 1];
    float ad = adb[node * 8 + hd];
    float m = -1e30f, l = 0.f, acc = 0.f;
    int s = csr_src[beg];
    for (int i = beg; i < end; ++i) {
        int s_next = (i + 1 < end) ? csr_src[i + 1] : s;
        float as = asb[s * 8 + hd];
        float hv = h[(size_t)s * 64 + lane];
        float v = as + ad;
        v = v > 0.f ? v : NEG_SLOPE * v;
        if (v > m) {
            float r = __expf(m - v);
            l *= r;
            acc *= r;
            m = v;
        }
        float w = __expf(v - m);
        l += w;
        acc += w * hv;
        s = s_next;
    }
    out[(size_t)node * 64 + lane] = acc / (l + 1e-16f) + bias[lane];
}

// =================== fused softmax+aggregate, width 40 (H=1,C=40) ========

__global__ __launch_bounds__(256) void aggr_csr40_k(
    const float* __restrict__ h, const float* __restrict__ asb,
    const float* __restrict__ adb, const int* __restrict__ row_ptr,
    const int* __restrict__ csr_src, float* __restrict__ out, int N) {
    int node = blockIdx.x * 4 + (threadIdx.x >> 6);
    if (node >= N) return;
    int lane = threadIdx.x & 63;
    int beg = row_ptr[node], end = row_ptr[node + 1];
    float ad = adb[node];
    float m = -1e30f, l = 0.f, acc = 0.f;
    int s = csr_src[beg];
    for (int i = beg; i < end; ++i) {
        int s_next = (i + 1 < end) ? csr_src[i + 1] : s;
        float as = asb[s];
        float hv = (lane < 40) ? h[(size_t)s * 40 + lane] : 0.f;
        float v = as + ad;
        v = v > 0.f ? v : NEG_SLOPE * v;
        if (v > m) {
            float r = __expf(m - v);
            l *= r;
            acc *= r;
            m = v;
        }
        float w = __expf(v - m);
        l += w;
        acc += w * hv;
        s = s_next;
    }
    if (lane < 40) out[(size_t)node * 40 + lane] = acc / (l + 1e-16f);
}

// =================== final: +bias, log_softmax over 40 classes ===========

__global__ void final_k(const float* __restrict__ agg,
                        const float* __restrict__ b, float* __restrict__ out,
                        int N) {
    int n = blockIdx.x * blockDim.x + threadIdx.x;
    if (n >= N) return;
    float v[40];
    float mx = -1e30f;
    #pragma unroll
    for (int j = 0; j < 40; ++j) {
        v[j] = agg[(size_t)n * 40 + j] + b[j];
        mx = fmaxf(mx, v[j]);
    }
    float ssum = 0.f;
    #pragma unroll
    for (int j = 0; j < 40; ++j) ssum += __expf(v[j] - mx);
    float lg = __logf(ssum);
    #pragma unroll
    for (int j = 0; j < 40; ++j) out[(size_t)n * 40 + j] = v[j] - mx - lg;
}

// =================== launch ===================

extern "C" void kernel_launch(void* const* d_in, const int* in_sizes, int n_in,
                              void* d_out, int out_size, void* d_ws,
                              size_t ws_size, hipStream_t stream) {
    const float* features = (const float*)d_in[0];
    const int* edge_index = (const int*)d_in[1];
    const float* W0 = (const float*)d_in[2];
    const float* as0 = (const float*)d_in[3];
    const float* ad0 = (const float*)d_in[4];
    const float* b0 = (const float*)d_in[5];
    const float* W1 = (const float*)d_in[6];
    const float* as1 = (const float*)d_in[7];
    const float* ad1 = (const float*)d_in[8];
    const float* b1 = (const float*)d_in[9];
    const float* W2 = (const float*)d_in[10];
    const float* as2 = (const float*)d_in[11];
    const float* ad2 = (const float*)d_in[12];
    const float* b2 = (const float*)d_in[13];

    int N = in_sizes[0] / 256;
    int E = in_sizes[1] / 2;
    int Etot = E + N;
    int nbuck = (N + 255) >> 8;  // 391 for N=100000 (must be <= 512)
    const int* srcs = edge_index;
    const int* dsts = edge_index + E;

    // workspace layout
    float* ws = (float*)d_ws;
    float* Hbuf = ws;                              // N*64 floats
    float* Abuf = Hbuf + (size_t)N * 64;           // N*64 floats
    float* asb  = Abuf + (size_t)N * 64;           // N*8
    float* adb  = asb + (size_t)N * 8;             // N*8
    int* row_ptr = (int*)(adb + (size_t)N * 8);    // N+1
    int* bcnt    = row_ptr + (N + 2);              // nbuck
    int* bptr    = bcnt + 512;                     // nbuck+1
    int* bcur    = bptr + 513;                     // nbuck
    int* csr_src = bcur + 512;                     // Etot
    int2* pairs  = (int2*)Hbuf;                    // Etot scratch (dead before gemm0)

    const int B = 256;
    int gN8 = (N * 8 + B - 1) / B;
    int gN1 = (N + B - 1) / B;
    int gAg = (N + 3) / 4;
    int gBk = (Etot + EPB - 1) / EPB;

    // ---------- CSR build (counting sort, no contended atomics) ----------
    hipMemsetAsync(bcnt, 0, 512 * 4, stream);
    bucket_hist_k<<<gBk, B, 0, stream>>>(dsts, bcnt, E, Etot, nbuck);
    bucket_scan_k<<<1, 512, 0, stream>>>(bcnt, bptr, bcur, nbuck, Etot);
    bucket_scatter_k<<<gBk, B, 0, stream>>>(srcs, dsts, bcur, pairs, E, Etot,
                                            nbuck);
    bucket_sort_k<<<nbuck, B, 0, stream>>>(pairs, bptr, row_ptr, csr_src, N,
                                           Etot, nbuck);

    // ---------------- layer 0 ----------------
    gemm0_k<<<(N + 15) / 16, B, 0, stream>>>(features, W0, Hbuf, N);
    att_k<8, 8><<<gN8, B, 0, stream>>>(Hbuf, as0, ad0, asb, adb, N);
    aggr_csr64_k<<<gAg, B, 0, stream>>>(Hbuf, asb, adb, row_ptr, csr_src, b0,
                                        Abuf, N);

    // ---------------- layer 1 ----------------
    gemm64_k<64><<<(N + 63) / 64, B, 0, stream>>>(Abuf, W1, Hbuf, N);
    att_k<8, 8><<<gN8, B, 0, stream>>>(Hbuf, as1, ad1, asb, adb, N);
    aggr_csr64_k<<<gAg, B, 0, stream>>>(Hbuf, asb, adb, row_ptr, csr_src, b1,
                                        Abuf, N);

    // ---------------- layer 2 ----------------
    gemm64_k<40><<<(N + 63) / 64, B, 0, stream>>>(Abuf, W2, Hbuf, N);
    att_k<1, 40><<<gN1, B, 0, stream>>>(Hbuf, as2, ad2, asb, adb, N);
    aggr_csr40_k<<<gAg, B, 0, stream>>>(Hbuf, asb, adb, row_ptr, csr_src,
                                        Abuf, N);
    final_k<<<gN1, B, 0, stream>>>(Abuf, b2, (float*)d_out, N);
}